// Round 3
// baseline (435.425 us; speedup 1.0000x reference)
//
#include <hip/hip_runtime.h>

// Problem constants
constexpr int CIN  = 32;
constexpr int COUT = 128;
constexpr int ATOM = 64;
constexpr int BB   = 128;
constexpr int COLS_PER_B = COUT * ATOM;              // 8192
constexpr long long NTOT = (long long)BB * COLS_PER_B; // 1,048,576 columns
constexpr float NTOTF = 1048576.0f;

// Native clang vector for nontemporal 16B stores (HIP float4 is a class type
// that __builtin_nontemporal_store rejects).
typedef float f32x4 __attribute__((ext_vector_type(4)));

// Stats kernel tiling
constexpr int TK    = 256;     // columns per LDS tile
constexpr int PAD   = 260;     // row stride in floats (multiple of 4 -> aligned b128; 260%32=4 spreads rows over banks)
constexpr int GRID1 = 1024;    // 4 blocks/CU
constexpr int TILES = 4096;    // NTOT / TK
constexpr int TPB   = TILES / GRID1; // 4 tiles per block

// ws layout (floats): [0..1023] G accum, [1024..1055] s accum,
//                     [1056..2079] W (invsqrt*gamma), [2080..2111] bias

__global__ __launch_bounds__(256) void stats_kernel(const float* __restrict__ x,
                                                    float* __restrict__ acc) {
    __shared__ float tile[CIN * PAD];   // 33,280 B
    __shared__ float ssum[CIN];
    const int t = threadIdx.x;
    const int w = t >> 6;        // wave id = k-quarter
    const int l = t & 63;
    const int ti = l >> 3;       // 0..7
    const int tj = l & 7;        // 0..7

    float accg[4][4] = {};
    float asum[4] = {0.f, 0.f, 0.f, 0.f};
    if (t < CIN) ssum[t] = 0.f;

    for (int tt = 0; tt < TPB; ++tt) {
        const int tileid = blockIdx.x * TPB + tt;
        const int b = tileid >> 5;               // 32 tiles per batch
        const int col0 = (tileid & 31) << 8;     // *256
        const float* xb = x + (size_t)b * CIN * COLS_PER_B + col0;

        __syncthreads();   // prev compute done (also covers ssum init)
        // stage: wave w loads rows {w, 4+w, ..., 28+w}, 1 KiB each, float4/lane
        #pragma unroll
        for (int rr = 0; rr < 8; ++rr) {
            const int row = rr * 4 + w;
            float4 v = *(const float4*)(xb + (size_t)row * COLS_PER_B + l * 4);
            *(float4*)(&tile[row * PAD + l * 4]) = v;
        }
        __syncthreads();

        // compute: wave w handles k in [w*64, w*64+64), float4 steps
        #pragma unroll
        for (int s = 0; s < 16; ++s) {
            const int k = w * 64 + s * 4;
            float4 av[4], bv[4];
            #pragma unroll
            for (int d = 0; d < 4; ++d) av[d] = *(const float4*)(&tile[(ti + 8 * d) * PAD + k]);
            #pragma unroll
            for (int d = 0; d < 4; ++d) bv[d] = *(const float4*)(&tile[(tj + 8 * d) * PAD + k]);
            #pragma unroll
            for (int di = 0; di < 4; ++di) {
                asum[di] += av[di].x + av[di].y + av[di].z + av[di].w;
                #pragma unroll
                for (int dj = 0; dj < 4; ++dj) {
                    accg[di][dj] += av[di].x * bv[dj].x + av[di].y * bv[dj].y
                                  + av[di].z * bv[dj].z + av[di].w * bv[dj].w;
                }
            }
        }
    }

    // cross-wave reduction of G partials via LDS (reuse tile)
    __syncthreads();
    #pragma unroll
    for (int di = 0; di < 4; ++di)
        #pragma unroll
        for (int dj = 0; dj < 4; ++dj)
            tile[w * 1024 + (ti + 8 * di) * 32 + (tj + 8 * dj)] = accg[di][dj];
    if (tj == 0) {
        #pragma unroll
        for (int di = 0; di < 4; ++di) atomicAdd(&ssum[ti + 8 * di], asum[di]);
    }
    __syncthreads();
    #pragma unroll
    for (int q = 0; q < 4; ++q) {
        const int idx = t + q * 256;
        const float v = tile[idx] + tile[1024 + idx] + tile[2048 + idx] + tile[3072 + idx];
        atomicAdd(&acc[idx], v);
    }
    if (t < CIN) atomicAdd(&acc[1024 + t], ssum[t]);
}

__global__ __launch_bounds__(1024) void newton_kernel(const float* __restrict__ acc,
                                                      const float* __restrict__ gamma,
                                                      const float* __restrict__ beta,
                                                      float* __restrict__ outp) {
    __shared__ float sn[32 * 33], p[32 * 33], t1[32 * 33], t2[32 * 33];
    __shared__ float mean[32], diag[32], trs[1];
    const int t = threadIdx.x;
    const int i = t >> 5, j = t & 31;

    if (t < 32) mean[t] = acc[1024 + t] * (1.0f / NTOTF);
    __syncthreads();
    const float sig = (acc[t] - NTOTF * mean[i] * mean[j]) * (1.0f / (NTOTF - 1.0f));
    if (i == j) diag[i] = sig;
    __syncthreads();
    if (t == 0) {
        float tr = 0.f;
        for (int k = 0; k < 32; ++k) tr += diag[k];
        trs[0] = tr;
    }
    __syncthreads();
    const float tr = trs[0];
    sn[i * 33 + j] = sig / tr;
    p[i * 33 + j]  = (i == j) ? 1.0f : 0.0f;
    __syncthreads();

    for (int it = 0; it < 5; ++it) {
        float a = 0.f;
        #pragma unroll
        for (int k = 0; k < 32; ++k) a += p[i * 33 + k] * p[k * 33 + j];
        t1[i * 33 + j] = a;
        __syncthreads();
        float c = 0.f;
        #pragma unroll
        for (int k = 0; k < 32; ++k) c += t1[i * 33 + k] * p[k * 33 + j];
        t2[i * 33 + j] = c;
        __syncthreads();
        float v = 0.f;
        #pragma unroll
        for (int k = 0; k < 32; ++k) v += t2[i * 33 + k] * sn[k * 33 + j];
        const float pn = 1.5f * p[i * 33 + j] - 0.5f * v;
        __syncthreads();
        p[i * 33 + j] = pn;
        __syncthreads();
    }

    const float r = rsqrtf(tr);
    const float wv = p[i * 33 + j] * r * gamma[j];   // fold gamma into W
    t1[i * 33 + j] = wv;
    outp[t] = wv;                                    // W: 1024 floats
    __syncthreads();
    if (t < 32) {
        float bb = beta[t];
        for (int k = 0; k < 32; ++k) bb -= mean[k] * t1[k * 33 + t];
        outp[1024 + t] = bb;                         // bias: 32 floats
    }
}

__global__ __launch_bounds__(256) void apply_kernel(const float* __restrict__ x,
                                                    const float* __restrict__ wm,
                                                    float* __restrict__ out) {
    // wm: [0..1023] W, [1024..1055] bias. Uniform indices -> s_load broadcasts.
    const size_t tid  = (size_t)blockIdx.x * 256 + threadIdx.x;
    const size_t col4 = tid * 4;          // 4 columns per thread
    const size_t b    = col4 >> 13;       // /8192
    const size_t c    = col4 & 8191;
    const float* xp = x + b * (size_t)(CIN * COLS_PER_B) + c;
    float* op       = out + b * (size_t)(CIN * COLS_PER_B) + c;

    float4 vals[32];
    #pragma unroll
    for (int i = 0; i < 32; ++i) vals[i] = *(const float4*)(xp + (size_t)i * COLS_PER_B);

    #pragma unroll
    for (int jb = 0; jb < 4; ++jb) {
        float4 accv[8];
        #pragma unroll
        for (int jj = 0; jj < 8; ++jj) {
            const float bv = wm[1024 + jb * 8 + jj];
            accv[jj] = make_float4(bv, bv, bv, bv);
        }
        #pragma unroll
        for (int i = 0; i < 32; ++i) {
            #pragma unroll
            for (int jj = 0; jj < 8; ++jj) {
                const float sv = wm[i * 32 + jb * 8 + jj];
                accv[jj].x += vals[i].x * sv;
                accv[jj].y += vals[i].y * sv;
                accv[jj].z += vals[i].z * sv;
                accv[jj].w += vals[i].w * sv;
            }
        }
        // Nontemporal: keep x resident in L3 (x re-read is the apply pass's
        // input; out is write-once and never re-read by us).
        #pragma unroll
        for (int jj = 0; jj < 8; ++jj) {
            f32x4 v = { accv[jj].x, accv[jj].y, accv[jj].z, accv[jj].w };
            __builtin_nontemporal_store(v, (f32x4*)(op + (size_t)(jb * 8 + jj) * COLS_PER_B));
        }
    }
}

extern "C" void kernel_launch(void* const* d_in, const int* in_sizes, int n_in,
                              void* d_out, int out_size, void* d_ws, size_t ws_size,
                              hipStream_t stream) {
    const float* x     = (const float*)d_in[0];
    const float* gamma = (const float*)d_in[1];
    const float* beta  = (const float*)d_in[2];
    float* out = (float*)d_out;
    float* acc = (float*)d_ws;            // 1056 accum + 1056 result floats

    (void)hipMemsetAsync(acc, 0, 1056 * sizeof(float), stream);
    stats_kernel<<<GRID1, 256, 0, stream>>>(x, acc);
    newton_kernel<<<1, 1024, 0, stream>>>(acc, gamma, beta, acc + 1056);
    apply_kernel<<<(NTOT / 4) / 256, 256, 0, stream>>>(x, acc + 1056, out);
}